// Round 1
// 785.511 us; speedup vs baseline: 1.0990x; 1.0990x over previous
//
#include <hip/hip_runtime.h>
#include <stdint.h>

typedef unsigned int u32;
typedef unsigned long long u64;
typedef unsigned short u16;

#define QN 32        // queries
#define DIM 128      // embedding dim
#define TILE_R 512   // corpus rows per block
#define CHUNK 32     // fp32 d-elements staged per chunk == MFMA K-step
#define NCHUNK (DIM / CHUNK)  // 4
#define KSEL 10      // top-k
#define MCHUNKS 8    // merge1 chunks per query

typedef __attribute__((ext_vector_type(8))) short s16x8;
typedef __attribute__((ext_vector_type(8))) __bf16 bf16x8;
typedef __attribute__((ext_vector_type(4))) float f32x4;

__device__ __forceinline__ u32 f2ord(float f) {
    u32 b = __float_as_uint(f);
    return b ^ (((int)b >> 31) | 0x80000000u);
}
__device__ __forceinline__ float ord2f(u32 e) {
    u32 b = (e & 0x80000000u) ? (e ^ 0x80000000u) : ~e;
    return __uint_as_float(b);
}
__device__ __forceinline__ u64 shfl_xor_u64(u64 v, int off) {
    return (u64)__shfl_xor((long long)v, off, 64);
}
__device__ __forceinline__ u64 wave_max_u64(u64 v) {
#pragma unroll
    for (int off = 1; off < 64; off <<= 1) {
        u64 o = shfl_xor_u64(v, off);
        if (o > v) v = o;
    }
    return v;
}

// fp32 -> bf16 round-to-nearest-even (bit trick, 3 VALU)
__device__ __forceinline__ u16 bfrne(float x) {
    u32 b = __float_as_uint(x);
    return (u16)((b + 0x7FFFu + ((b >> 16) & 1u)) >> 16);
}

// 3-way Dekker split of 8 fp32 into bf16 hi/mid/lo fragments.
// x = hi + mid + lo + eps, |eps| <= 2^-24 |x| (subtractions are Sterbenz-exact).
__device__ __forceinline__ void split3(float4 a, float4 b,
                                       s16x8& h, s16x8& m, s16x8& l) {
    float x[8] = {a.x, a.y, a.z, a.w, b.x, b.y, b.z, b.w};
#pragma unroll
    for (int i = 0; i < 8; ++i) {
        u16 hs = bfrne(x[i]);
        float hf = __uint_as_float((u32)hs << 16);
        float r = x[i] - hf;
        u16 ms = bfrne(r);
        float mf = __uint_as_float((u32)ms << 16);
        float r2 = r - mf;
        u16 lsv = bfrne(r2);
        h[i] = (short)hs;
        m[i] = (short)ms;
        l[i] = (short)lsv;
    }
}

__device__ __forceinline__ f32x4 mfma16(s16x8 a, s16x8 b, f32x4 c) {
    return __builtin_amdgcn_mfma_f32_16x16x32_bf16(
        __builtin_bit_cast(bf16x8, a), __builtin_bit_cast(bf16x8, b), c, 0, 0, 0);
}

// guarded sorted-insert into descending top-10 list (all static indices)
__device__ __forceinline__ void ins10(u64 (&h)[KSEL], u64 kk) {
    if (kk > h[KSEL - 1]) {
#pragma unroll
        for (int t = KSEL - 1; t > 0; --t)
            if (kk > h[t]) h[t] = (kk > h[t - 1]) ? h[t - 1] : kk;
        if (kk > h[0]) h[0] = kk;
    }
}

// Pass 1: each block scores TILE_R rows against all 32 queries via bf16x3-split
// MFMA (6 terms: hh,hm,mh,mm,hl,lh -> fp32-accurate), emits block top-10 packed
// (score*invc, ~idx) u64 keys per query.  invq deferred to merge2 (per-query
// positive scale; ranking invariant).
// MFMA 16x16x32 layouts: A lane: m=l&15, k=(l>>4)*8+i.  B lane: n=l&15,
// k=(l>>4)*8+i.  C/D: col(n)=l&15, row(m)=(l>>4)*4+reg  [m89-verified].
// LDS tiles XOR-swizzled (slot ^= row&7) via pre-swizzled global source so
// global_load_lds stays linear and ds_read_b128 avoids row-stride conflicts.
__launch_bounds__(256, 2)
__global__ void score_topk(const float* __restrict__ qry,
                           const float* __restrict__ corpus,
                           u64* __restrict__ cand_k,
                           int n, int nb) {
    __shared__ float lds_q[QN * DIM];        // 16 KB, f4-slot swizzled per row
    __shared__ float lds_c[TILE_R * CHUNK];  // 64 KB, one K-chunk of 512 rows

    const int tid = threadIdx.x;
    const int w = tid >> 6;   // wave id: owns rows [w*128, w*128+128)
    const int l = tid & 63;
    const int tile_base = blockIdx.x * TILE_R;

    const int lo4 = l & 15, hi4 = l >> 4, l7 = l & 7, l3 = l >> 3;

    // stage queries (coalesced read; swizzled write: phys_d4 = d4 ^ (q&7))
    {
        const float4* qg = (const float4*)qry;
        float4* ql = (float4*)lds_q;
#pragma unroll
        for (int i0 = 0; i0 < QN * DIM / 4; i0 += 256) {
            int i = i0 + tid;
            int q = i >> 5, d4 = i & 31;
            ql[(q << 5) | (d4 ^ (q & 7))] = qg[i];
        }
    }

    f32x4 acc[2][8];   // [n-tile (q 0-15 / 16-31)][m-tile] - static indexed only
    float ss[8];       // row sum-of-squares quarter-partials (row = mt*16+lo4)
#pragma unroll
    for (int mt = 0; mt < 8; ++mt) {
        ss[mt] = 0.f;
        acc[0][mt] = (f32x4){0.f, 0.f, 0.f, 0.f};
        acc[1][mt] = (f32x4){0.f, 0.f, 0.f, 0.f};
    }

    // per-lane fragment byte offsets (chunk-invariant)
    const int arow = (w * 128 + lo4) * 128;                    // A row byte base
    const int aoff0 = arow + (((hi4 * 2 + 0) ^ l7) << 4);
    const int aoff1 = arow + (((hi4 * 2 + 1) ^ l7) << 4);
    const int boff0 = lo4 * 512 + (((hi4 * 2 + 0) ^ l7) << 4); // + nt*8192 + c*128
    const int boff1 = lo4 * 512 + (((hi4 * 2 + 1) ^ l7) << 4);

#pragma unroll 1
    for (int c = 0; c < NCHUNK; ++c) {
        __syncthreads();  // prev chunk consumed (c=0: queries visible)
        // stage rows [w*128, w*128+128) x 32 d: 16 insts x (8 rows x 8 f4 slots)
        // source pre-swizzled: slot_log = (l&7) ^ (l>>3) so linear LDS dest
        // yields phys = s_log ^ (row&7)
        {
            const float* gsrc = corpus + c * CHUNK + ((l7 ^ l3) << 2);
#pragma unroll
            for (int j = 0; j < 16; ++j) {
                int rbase = w * 128 + j * 8;
                int grow = tile_base + rbase + l3;
                if (grow >= n) grow = n - 1;       // clamp; masked at key build
                float* lp = lds_c + rbase * CHUNK; // wave-uniform; HW adds lane*16
                __builtin_amdgcn_global_load_lds(
                    (const __attribute__((address_space(1))) void*)(gsrc + (size_t)grow * DIM),
                    (__attribute__((address_space(3))) void*)lp, 16, 0, 0);
            }
        }
        __syncthreads();  // drains vmcnt -> staged data visible

        // B fragments for this chunk (k = hi4*8 + i within chunk)
        s16x8 bh[2], bm[2], bl[2];
#pragma unroll
        for (int nt = 0; nt < 2; ++nt) {
            const char* bp = (const char*)lds_q + nt * 8192 + c * 128;
            float4 q0 = *(const float4*)(bp + boff0);
            float4 q1 = *(const float4*)(bp + boff1);
            split3(q0, q1, bh[nt], bm[nt], bl[nt]);
        }

#pragma unroll
        for (int mt = 0; mt < 8; ++mt) {
            const char* ap = (const char*)lds_c + mt * 2048;
            float4 a0 = *(const float4*)(ap + aoff0);
            float4 a1 = *(const float4*)(ap + aoff1);
            float s2 = ss[mt];
            s2 = fmaf(a0.x, a0.x, s2); s2 = fmaf(a0.y, a0.y, s2);
            s2 = fmaf(a0.z, a0.z, s2); s2 = fmaf(a0.w, a0.w, s2);
            s2 = fmaf(a1.x, a1.x, s2); s2 = fmaf(a1.y, a1.y, s2);
            s2 = fmaf(a1.z, a1.z, s2); s2 = fmaf(a1.w, a1.w, s2);
            ss[mt] = s2;
            s16x8 ah, am, al;
            split3(a0, a1, ah, am, al);
#pragma unroll
            for (int nt = 0; nt < 2; ++nt) {
                f32x4 cc = acc[nt][mt];
                cc = mfma16(ah, bh[nt], cc);
                cc = mfma16(ah, bm[nt], cc);
                cc = mfma16(am, bh[nt], cc);
                cc = mfma16(am, bm[nt], cc);
                cc = mfma16(ah, bl[nt], cc);
                cc = mfma16(al, bh[nt], cc);
                acc[nt][mt] = cc;
            }
        }
    }
    __syncthreads();  // all waves done reading lds_c before reuse

    // corpus inverse norms: combine 4 k-quarter partials (lanes l^16, l^32)
    float invco[8];
#pragma unroll
    for (int mt = 0; mt < 8; ++mt) {
        float s2 = ss[mt];
        s2 += __shfl_xor(s2, 16, 64);
        s2 += __shfl_xor(s2, 32, 64);
        invco[mt] = rsqrtf(fmaxf(s2, 1e-24f));  // valid for row mt*16+lo4
    }

    // per-lane top-10 per owned query (nt=0: q=lo4, nt=1: q=16+lo4) over its
    // 32 rows (mt 0..7 x reg 0..3, row = mt*16 + hi4*4 + reg)
    u64 h0[KSEL], h1[KSEL];
#pragma unroll
    for (int i = 0; i < KSEL; ++i) { h0[i] = 0ull; h1[i] = 0ull; }

#pragma unroll
    for (int mt = 0; mt < 8; ++mt) {
        float ic[4];
#pragma unroll
        for (int r = 0; r < 4; ++r)  // invc lives at lanes with lo4 == row
            ic[r] = __shfl(invco[mt], (l & 48) | (hi4 * 4 + r), 64);
        const int gbase = tile_base + w * 128 + mt * 16 + hi4 * 4;
#pragma unroll
        for (int r = 0; r < 4; ++r) {
            int gidx = gbase + r;
            u32 iv = (u32)(~(u32)gidx);  // tie -> lower idx
            bool ok = (gidx < n);
            {
                float sc = acc[0][mt][r] * ic[r];
                u64 kk = ((u64)f2ord(sc) << 32) | iv;
                ins10(h0, ok ? kk : 0ull);
            }
            {
                float sc = acc[1][mt][r] * ic[r];
                u64 kk = ((u64)f2ord(sc) << 32) | iv;
                ins10(h1, ok ? kk : 0ull);
            }
        }
    }

    // dump per-lane lists to LDS (40 KB, reuses lds_c), then 8-lane-group merge
    u64* lbuf = (u64*)lds_c;
    {
        int base = (w * 64 + l) * 2 * KSEL;
#pragma unroll
        for (int i = 0; i < KSEL; ++i) lbuf[base + i] = h0[i];
#pragma unroll
        for (int i = 0; i < KSEL; ++i) lbuf[base + KSEL + i] = h1[i];
    }
    __syncthreads();

    // block-level top-10 per query: wave w handles queries w*8..w*8+7,
    // 8 lanes per query, each merging 2 of the 16 source lists (4 waves x 4 lanes)
    {
        const int g = l >> 3, j = l & 7;
        const int q = w * 8 + g;
        const int nt = q >> 4, qlow = q & 15;
        u64 hh[KSEL];
#pragma unroll
        for (int i = 0; i < KSEL; ++i) hh[i] = 0ull;
#pragma unroll
        for (int t = 0; t < 2; ++t) {
            int rid = j * 2 + t;
            int wv = rid >> 2, ls = qlow + (rid & 3) * 16;
            int base = ((wv * 64 + ls) * 2 + nt) * KSEL;
#pragma unroll
            for (int i = 0; i < KSEL; ++i) ins10(hh, lbuf[base + i]);
        }
#pragma unroll 1
        for (int rank = 0; rank < KSEL; ++rank) {
            u64 cand = hh[0];
            u64 win = cand;
#pragma unroll
            for (int off = 1; off < 8; off <<= 1) {  // butterfly within 8-lane group
                u64 o = shfl_xor_u64(win, off);
                if (o > win) win = o;
            }
            if (cand == win) {  // unique owner pops (keys unique: distinct idx)
#pragma unroll
                for (int i = 0; i < KSEL - 1; ++i) hh[i] = hh[i + 1];
                hh[KSEL - 1] = 0ull;
            }
            if (j == 0)
                cand_k[((size_t)q * nb + blockIdx.x) * KSEL + rank] = win;
        }
    }
}

// Pass 2a: one wave per (query, chunk); ~2443 candidates -> top-10.
__launch_bounds__(64)
__global__ void merge1(const u64* __restrict__ cand_k,
                       u64* __restrict__ cand2, int total) {
    const int q = blockIdx.x >> 3;
    const int ch = blockIdx.x & 7;
    const int T = (total + MCHUNKS - 1) / MCHUNKS;
    const int start = ch * T;
    const int cnt = min(T, total - start);
    const int l = threadIdx.x;

    u64 h[KSEL];
#pragma unroll
    for (int i = 0; i < KSEL; ++i) h[i] = 0ull;

    for (int j = l; j < cnt; j += 64) {
        u64 kk = cand_k[(size_t)q * total + start + j];
        if (kk > h[KSEL - 1]) {
#pragma unroll
            for (int t = KSEL - 1; t > 0; --t) {
                if (kk > h[t]) h[t] = (kk > h[t - 1]) ? h[t - 1] : kk;
            }
            if (kk > h[0]) h[0] = kk;
        }
    }

    int p = 0;
#pragma unroll 1
    for (int rank = 0; rank < KSEL; ++rank) {
        u64 cand = (p < KSEL) ? h[p] : 0ull;
        u64 win = wave_max_u64(cand);
        if (cand == win && win) ++p;
        if (l == 0) cand2[(size_t)(q * MCHUNKS + ch) * KSEL + rank] = win;
    }
}

// Pass 2b: one wave per query merges 80 candidates -> final top-10.
// Applies the deferred per-query inverse norm to the output scores.
__launch_bounds__(64)
__global__ void merge2(const u64* __restrict__ cand2,
                       const float* __restrict__ qry,
                       float* __restrict__ out, int qn) {
    const int q = blockIdx.x;
    const int l = threadIdx.x;
    const int total = MCHUNKS * KSEL;  // 80

    float2 v = *(const float2*)(qry + q * DIM + 2 * l);
    float p = v.x * v.x + v.y * v.y;
#pragma unroll
    for (int off = 32; off; off >>= 1) p += __shfl_xor(p, off, 64);
    const float invq = rsqrtf(fmaxf(p, 1e-24f));

    u64 K[2];
#pragma unroll
    for (int i = 0; i < 2; ++i) {
        int jj = l + i * 64;
        K[i] = (jj < total) ? cand2[(size_t)q * total + jj] : 0ull;
    }

#pragma unroll 1
    for (int rank = 0; rank < KSEL; ++rank) {
        u64 m = (K[0] > K[1]) ? K[0] : K[1];
        u64 win = wave_max_u64(m);
#pragma unroll
        for (int i = 0; i < 2; ++i)
            if (K[i] == win) K[i] = 0ull;
        if (l == 0) {
            out[q * KSEL + rank] = ord2f((u32)(win >> 32)) * invq;
            out[qn * KSEL + q * KSEL + rank] = (float)(int)(~(u32)win);
        }
    }
}

extern "C" void kernel_launch(void* const* d_in, const int* in_sizes, int n_in,
                              void* d_out, int out_size, void* d_ws, size_t ws_size,
                              hipStream_t stream) {
    const float* qry = (const float*)d_in[0];
    const float* corpus = (const float*)d_in[1];
    const int qn = in_sizes[0] / DIM;          // 32
    const int n = in_sizes[1] / DIM;           // 1,000,000
    const int nb = (n + TILE_R - 1) / TILE_R;  // 1954
    const int total = nb * KSEL;               // candidates per query

    u64* cand_k = (u64*)d_ws;
    u64* cand2 = cand_k + (size_t)qn * total;

    score_topk<<<dim3(nb), dim3(256), 0, stream>>>(qry, corpus, cand_k, n, nb);
    merge1<<<dim3(qn * MCHUNKS), dim3(64), 0, stream>>>(cand_k, cand2, total);
    merge2<<<dim3(qn), dim3(64), 0, stream>>>(cand2, qry, (float*)d_out, qn);
}

// Round 2
// 776.636 us; speedup vs baseline: 1.1116x; 1.0114x over previous
//
#include <hip/hip_runtime.h>
#include <stdint.h>

typedef unsigned int u32;
typedef unsigned long long u64;

#define QN 32        // queries
#define DIM 128      // embedding dim
#define TILE_R 256   // corpus rows per block (halved: enables LDS double-buffer)
#define CHUNK 32     // fp32 d-elements staged per chunk == MFMA K-step
#define NCHUNK (DIM / CHUNK)  // 4
#define KSEL 10      // top-k
#define MCHUNKS 16   // merge1 chunks per query

typedef __attribute__((ext_vector_type(8))) __bf16 bf16x8;
typedef __attribute__((ext_vector_type(4))) float f32x4;

__device__ __forceinline__ u32 f2ord(float f) {
    u32 b = __float_as_uint(f);
    return b ^ (((int)b >> 31) | 0x80000000u);
}
__device__ __forceinline__ float ord2f(u32 e) {
    u32 b = (e & 0x80000000u) ? (e ^ 0x80000000u) : ~e;
    return __uint_as_float(b);
}
__device__ __forceinline__ u64 shfl_xor_u64(u64 v, int off) {
    return (u64)__shfl_xor((long long)v, off, 64);
}
__device__ __forceinline__ u64 wave_max_u64(u64 v) {
#pragma unroll
    for (int off = 1; off < 64; off <<= 1) {
        u64 o = shfl_xor_u64(v, off);
        if (o > v) v = o;
    }
    return v;
}

// 3-way split of 8 fp32 into bf16 hi/mid/lo via native casts: the compiler
// packs pairs into v_cvt_pk_bf16_f32 (m240) -> ~6 VALU/elem vs ~13 for the
// bit-trick version.  x = h + m + l + eps, |eps| <= 2^-27 |x|.
__device__ __forceinline__ void split3(float4 a, float4 b,
                                       bf16x8& h, bf16x8& m, bf16x8& l) {
    float x[8] = {a.x, a.y, a.z, a.w, b.x, b.y, b.z, b.w};
#pragma unroll
    for (int i = 0; i < 8; ++i) {
        __bf16 hb = (__bf16)x[i];
        float r = x[i] - (float)hb;
        __bf16 mb = (__bf16)r;
        float r2 = r - (float)mb;
        h[i] = hb; m[i] = mb; l[i] = (__bf16)r2;
    }
}

__device__ __forceinline__ f32x4 mfma16(bf16x8 a, bf16x8 b, f32x4 c) {
    return __builtin_amdgcn_mfma_f32_16x16x32_bf16(a, b, c, 0, 0, 0);
}

// guarded sorted-insert into descending top-10 list (all static indices)
__device__ __forceinline__ void ins10(u64 (&h)[KSEL], u64 kk) {
    if (kk > h[KSEL - 1]) {
#pragma unroll
        for (int t = KSEL - 1; t > 0; --t)
            if (kk > h[t]) h[t] = (kk > h[t - 1]) ? h[t - 1] : kk;
        if (kk > h[0]) h[0] = kk;
    }
}

// Pass 1: each block scores TILE_R rows against 32 queries via bf16x3-split
// MFMA (6 terms: hh,hm,mh,mm,hl,lh -> fp32-accurate).  invq deferred to merge2.
//
// BARRIER-FREE K-loop: each wave stages AND consumes only its own 64-row slice
// of lds_c, so no cross-wave hazard exists between chunks.  Per-wave LDS
// double-buffer + counted `s_waitcnt vmcnt(8)` (waits only the previous
// chunk's 8 global_load_lds; vmcnt is per-wave) lets HBM latency+BW hide
// under split3+MFMA of the current chunk.  Only 2 __syncthreads total
// (prologue: queries visible; epilogue: lds_c reuse as merge buffer).
//
// MFMA 16x16x32 layouts: A lane: m=l&15, k=(l>>4)*8+i.  B lane: n=l&15,
// k=(l>>4)*8+i.  C/D: col(n)=l&15, row(m)=(l>>4)*4+reg  [m89-verified].
// LDS XOR-swizzled (f4-slot ^= row&7) via pre-swizzled global source so
// global_load_lds stays linear and ds_read_b128 avoids row-stride conflicts.
__launch_bounds__(256, 2)
__global__ void score_topk(const float* __restrict__ qry,
                           const float* __restrict__ corpus,
                           u64* __restrict__ cand_k,
                           int n, int nb) {
    __shared__ float lds_q[QN * DIM];           // 16 KB, f4-slot swizzled
    __shared__ float lds_c[2][TILE_R * CHUNK];  // 2 x 32 KB double buffer

    const int tid = threadIdx.x;
    const int w = tid >> 6;   // wave id: owns rows [w*64, w*64+64)
    const int l = tid & 63;
    const int tile_base = blockIdx.x * TILE_R;

    const int lo4 = l & 15, hi4 = l >> 4, l7 = l & 7, l3 = l >> 3;

    // stage queries (coalesced read; swizzled write: phys_d4 = d4 ^ (q&7))
    {
        const float4* qg = (const float4*)qry;
        float4* ql = (float4*)lds_q;
#pragma unroll
        for (int i0 = 0; i0 < QN * DIM / 4; i0 += 256) {
            int i = i0 + tid;
            int q = i >> 5, d4 = i & 31;
            ql[(q << 5) | (d4 ^ (q & 7))] = qg[i];
        }
    }

    f32x4 acc[2][4];   // [n-tile (q 0-15 / 16-31)][m-tile] - static indexed only
    float ss[4];       // row sum-of-squares quarter-partials (row = mt*16+lo4)
#pragma unroll
    for (int mt = 0; mt < 4; ++mt) {
        ss[mt] = 0.f;
        acc[0][mt] = (f32x4){0.f, 0.f, 0.f, 0.f};
        acc[1][mt] = (f32x4){0.f, 0.f, 0.f, 0.f};
    }

    // per-lane fragment byte offsets (chunk-invariant)
    const int arow = (w * 64 + lo4) * 128;                     // A row byte base
    const int aoff0 = arow + (((hi4 * 2 + 0) ^ l7) << 4);
    const int aoff1 = arow + (((hi4 * 2 + 1) ^ l7) << 4);
    const int boff0 = lo4 * 512 + (((hi4 * 2 + 0) ^ l7) << 4); // + nt*8192 + c*128
    const int boff1 = lo4 * 512 + (((hi4 * 2 + 1) ^ l7) << 4);
    const int slotoff = (l7 ^ l3) << 2;  // source pre-swizzle: phys slot l7
                                         // holds logical slot l7 ^ (row&7)

    // stage own 64 rows x 32 d of chunk c: 8 insts x (8 rows x 8 f4 slots)
    auto STAGE = [&](int c, float* buf) {
        const float* gsrc = corpus + c * CHUNK + slotoff;
#pragma unroll
        for (int j = 0; j < 8; ++j) {
            int rbase = w * 64 + j * 8;
            int grow = tile_base + rbase + l3;
            if (grow >= n) grow = n - 1;       // clamp; masked at key build
            float* lp = buf + rbase * CHUNK;   // wave-uniform; HW adds lane*16
            __builtin_amdgcn_global_load_lds(
                (const __attribute__((address_space(1))) void*)(gsrc + (size_t)grow * DIM),
                (__attribute__((address_space(3))) void*)lp, 16, 0, 0);
        }
    };

    auto COMPUTE = [&](int c, const float* buf) {
        bf16x8 bh[2], bm[2], bl[2];
#pragma unroll
        for (int nt = 0; nt < 2; ++nt) {   // wave-uniform rows -> LDS broadcast
            const char* bp = (const char*)lds_q + nt * 8192 + c * 128;
            float4 q0 = *(const float4*)(bp + boff0);
            float4 q1 = *(const float4*)(bp + boff1);
            split3(q0, q1, bh[nt], bm[nt], bl[nt]);
        }
#pragma unroll
        for (int mt = 0; mt < 4; ++mt) {
            const char* ap = (const char*)buf + mt * 2048;
            float4 a0 = *(const float4*)(ap + aoff0);
            float4 a1 = *(const float4*)(ap + aoff1);
            float s2 = ss[mt];
            s2 = fmaf(a0.x, a0.x, s2); s2 = fmaf(a0.y, a0.y, s2);
            s2 = fmaf(a0.z, a0.z, s2); s2 = fmaf(a0.w, a0.w, s2);
            s2 = fmaf(a1.x, a1.x, s2); s2 = fmaf(a1.y, a1.y, s2);
            s2 = fmaf(a1.z, a1.z, s2); s2 = fmaf(a1.w, a1.w, s2);
            ss[mt] = s2;
            bf16x8 ah, am, al;
            split3(a0, a1, ah, am, al);
#pragma unroll
            for (int nt = 0; nt < 2; ++nt) {
                f32x4 cc = acc[nt][mt];
                cc = mfma16(ah, bh[nt], cc);
                cc = mfma16(ah, bm[nt], cc);
                cc = mfma16(am, bh[nt], cc);
                cc = mfma16(am, bm[nt], cc);
                cc = mfma16(ah, bl[nt], cc);
                cc = mfma16(al, bh[nt], cc);
                acc[nt][mt] = cc;
            }
        }
    };

    // pipeline: stage(c+1) in flight while computing c; per-wave vmcnt(8)
    // waits only the 8 oldest loads (= the buffer about to be read).
    STAGE(0, lds_c[0]);
    __syncthreads();                       // queries + chunk0 visible
    STAGE(1, lds_c[1]);
    COMPUTE(0, lds_c[0]);
    STAGE(2, lds_c[0]);                    // own reads of buf0 already consumed
    asm volatile("s_waitcnt vmcnt(8)" ::: "memory");  // stage1 complete
    COMPUTE(1, lds_c[1]);
    STAGE(3, lds_c[1]);
    asm volatile("s_waitcnt vmcnt(8)" ::: "memory");  // stage2 complete
    COMPUTE(2, lds_c[0]);
    asm volatile("s_waitcnt vmcnt(0)" ::: "memory");  // stage3 complete
    COMPUTE(3, lds_c[1]);
    __syncthreads();                       // all waves done before lds_c reuse

    // corpus inverse norms: combine 4 k-quarter partials (lanes l^16, l^32)
    float invco[4];
#pragma unroll
    for (int mt = 0; mt < 4; ++mt) {
        float s2 = ss[mt];
        s2 += __shfl_xor(s2, 16, 64);
        s2 += __shfl_xor(s2, 32, 64);
        invco[mt] = rsqrtf(fmaxf(s2, 1e-24f));  // valid for row mt*16+lo4
    }

    // per-lane top-10 per owned query (nt=0: q=lo4, nt=1: q=16+lo4) over its
    // 16 rows (mt 0..3 x reg 0..3, row = mt*16 + hi4*4 + reg)
    u64 h0[KSEL], h1[KSEL];
#pragma unroll
    for (int i = 0; i < KSEL; ++i) { h0[i] = 0ull; h1[i] = 0ull; }

#pragma unroll
    for (int mt = 0; mt < 4; ++mt) {
        float ic[4];
#pragma unroll
        for (int r = 0; r < 4; ++r)  // invc lives at lanes with lo4 == row
            ic[r] = __shfl(invco[mt], (l & 48) | (hi4 * 4 + r), 64);
        const int gbase = tile_base + w * 64 + mt * 16 + hi4 * 4;
#pragma unroll
        for (int r = 0; r < 4; ++r) {
            int gidx = gbase + r;
            u32 iv = (u32)(~(u32)gidx);  // tie -> lower idx
            bool ok = (gidx < n);
            {
                float sc = acc[0][mt][r] * ic[r];
                u64 kk = ((u64)f2ord(sc) << 32) | iv;
                ins10(h0, ok ? kk : 0ull);
            }
            {
                float sc = acc[1][mt][r] * ic[r];
                u64 kk = ((u64)f2ord(sc) << 32) | iv;
                ins10(h1, ok ? kk : 0ull);
            }
        }
    }

    // dump per-lane lists to LDS (40 KB, reuses lds_c), then 8-lane-group merge
    u64* lbuf = (u64*)&lds_c[0][0];
    {
        int base = tid * 2 * KSEL;
#pragma unroll
        for (int i = 0; i < KSEL; ++i) lbuf[base + i] = h0[i];
#pragma unroll
        for (int i = 0; i < KSEL; ++i) lbuf[base + KSEL + i] = h1[i];
    }
    __syncthreads();

    // block-level top-10 per query: wave w handles queries w*8..w*8+7,
    // 8 lanes per query, each merging 2 of the 16 source lists (4 waves x 4 hi4)
    {
        const int g = l >> 3, j = l & 7;
        const int q = w * 8 + g;
        const int nt = q >> 4, qlow = q & 15;
        u64 hh[KSEL];
#pragma unroll
        for (int i = 0; i < KSEL; ++i) hh[i] = 0ull;
#pragma unroll
        for (int t = 0; t < 2; ++t) {
            int rid = j * 2 + t;
            int wv = rid >> 2, ls = qlow + (rid & 3) * 16;
            int base = ((wv * 64 + ls) * 2 + nt) * KSEL;
#pragma unroll
            for (int i = 0; i < KSEL; ++i) ins10(hh, lbuf[base + i]);
        }
#pragma unroll 1
        for (int rank = 0; rank < KSEL; ++rank) {
            u64 cand = hh[0];
            u64 win = cand;
#pragma unroll
            for (int off = 1; off < 8; off <<= 1) {  // butterfly in 8-lane group
                u64 o = shfl_xor_u64(win, off);
                if (o > win) win = o;
            }
            if (cand == win) {  // unique owner pops (keys unique: distinct idx)
#pragma unroll
                for (int i = 0; i < KSEL - 1; ++i) hh[i] = hh[i + 1];
                hh[KSEL - 1] = 0ull;
            }
            if (j == 0)
                cand_k[((size_t)q * nb + blockIdx.x) * KSEL + rank] = win;
        }
    }
}

// Pass 2a: one wave per (query, chunk); ~2442 candidates -> top-10.
__launch_bounds__(64)
__global__ void merge1(const u64* __restrict__ cand_k,
                       u64* __restrict__ cand2, int total) {
    const int q = blockIdx.x >> 4;
    const int ch = blockIdx.x & 15;
    const int T = (total + MCHUNKS - 1) / MCHUNKS;
    const int start = ch * T;
    const int cnt = min(T, total - start);
    const int l = threadIdx.x;

    u64 h[KSEL];
#pragma unroll
    for (int i = 0; i < KSEL; ++i) h[i] = 0ull;

    for (int j = l; j < cnt; j += 64) {
        u64 kk = cand_k[(size_t)q * total + start + j];
        if (kk > h[KSEL - 1]) {
#pragma unroll
            for (int t = KSEL - 1; t > 0; --t) {
                if (kk > h[t]) h[t] = (kk > h[t - 1]) ? h[t - 1] : kk;
            }
            if (kk > h[0]) h[0] = kk;
        }
    }

    int p = 0;
#pragma unroll 1
    for (int rank = 0; rank < KSEL; ++rank) {
        u64 cand = (p < KSEL) ? h[p] : 0ull;
        u64 win = wave_max_u64(cand);
        if (cand == win && win) ++p;
        if (l == 0) cand2[(size_t)(q * MCHUNKS + ch) * KSEL + rank] = win;
    }
}

// Pass 2b: one wave per query merges 160 candidates -> final top-10.
// Applies the deferred per-query inverse norm to the output scores.
__launch_bounds__(64)
__global__ void merge2(const u64* __restrict__ cand2,
                       const float* __restrict__ qry,
                       float* __restrict__ out, int qn) {
    const int q = blockIdx.x;
    const int l = threadIdx.x;
    const int total = MCHUNKS * KSEL;  // 160

    float2 v = *(const float2*)(qry + q * DIM + 2 * l);
    float p = v.x * v.x + v.y * v.y;
#pragma unroll
    for (int off = 32; off; off >>= 1) p += __shfl_xor(p, off, 64);
    const float invq = rsqrtf(fmaxf(p, 1e-24f));

    u64 K[3];
#pragma unroll
    for (int i = 0; i < 3; ++i) {
        int jj = l + i * 64;
        K[i] = (jj < total) ? cand2[(size_t)q * total + jj] : 0ull;
    }

#pragma unroll 1
    for (int rank = 0; rank < KSEL; ++rank) {
        u64 m = (K[0] > K[1]) ? K[0] : K[1];
        m = (K[2] > m) ? K[2] : m;
        u64 win = wave_max_u64(m);
#pragma unroll
        for (int i = 0; i < 3; ++i)
            if (K[i] == win) K[i] = 0ull;
        if (l == 0) {
            out[q * KSEL + rank] = ord2f((u32)(win >> 32)) * invq;
            out[qn * KSEL + q * KSEL + rank] = (float)(int)(~(u32)win);
        }
    }
}

extern "C" void kernel_launch(void* const* d_in, const int* in_sizes, int n_in,
                              void* d_out, int out_size, void* d_ws, size_t ws_size,
                              hipStream_t stream) {
    const float* qry = (const float*)d_in[0];
    const float* corpus = (const float*)d_in[1];
    const int qn = in_sizes[0] / DIM;          // 32
    const int n = in_sizes[1] / DIM;           // 1,000,000
    const int nb = (n + TILE_R - 1) / TILE_R;  // 3907
    const int total = nb * KSEL;               // candidates per query

    u64* cand_k = (u64*)d_ws;
    u64* cand2 = cand_k + (size_t)qn * total;

    score_topk<<<dim3(nb), dim3(256), 0, stream>>>(qry, corpus, cand_k, n, nb);
    merge1<<<dim3(qn * MCHUNKS), dim3(64), 0, stream>>>(cand_k, cand2, total);
    merge2<<<dim3(qn), dim3(64), 0, stream>>>(cand2, qry, (float*)d_out, qn);
}